// Round 1
// baseline (1122.130 us; speedup 1.0000x reference)
//
#include <hip/hip_runtime.h>
#include <cmath>
#include <cstdint>

// Problem constants
#define B_N  64
#define W_N  16
#define C_N  64
#define T_N  1024
#define BW_N 1024           // B*W
#define DE_N 64
#define AIDX(i,j) ((i)*65 + (j))   // +1 pad (stride 65) to break stride-64 LDS bank conflicts

// ---------------------------------------------------------------------------
// K1: per-(b,w,c) stats over T.  One wave per row of 1024 floats.
// stat = 0.5*(mean + energy), accumulated in fp64, stored transposed [C][BW].
// ---------------------------------------------------------------------------
__global__ __launch_bounds__(256) void k_stats(const float* __restrict__ x,
                                               double* __restrict__ statT) {
  int wid  = (blockIdx.x << 2) + (threadIdx.x >> 6);  // row id = bw*64 + c, 0..65535
  int lane = threadIdx.x & 63;
  const float4* xp = (const float4*)(x + (size_t)wid * T_N);
  double s = 0.0, q = 0.0;
#pragma unroll
  for (int k = 0; k < 4; ++k) {
    float4 v = xp[lane + (k << 6)];
    double a0 = v.x, a1 = v.y, a2 = v.z, a3 = v.w;
    s += (a0 + a1) + (a2 + a3);
    q += (a0*a0 + a1*a1) + (a2*a2 + a3*a3);
  }
#pragma unroll
  for (int off = 32; off; off >>= 1) {
    s += __shfl_down(s, off, 64);
    q += __shfl_down(q, off, 64);
  }
  if (lane == 0) {
    int bw = wid >> 6, c = wid & 63;
    statT[c * BW_N + bw] = 0.5 * (s * (1.0 / T_N) + q * (1.0 / T_N));
  }
}

// ---------------------------------------------------------------------------
// K2: Z[c][e] = mean_{bw} tanh(stat[bw][c] * Wp[e]).  One wave per (c,e).
// ---------------------------------------------------------------------------
__global__ __launch_bounds__(256) void k_embed(const double* __restrict__ statT,
                                               const float* __restrict__ Wp,
                                               double* __restrict__ Z) {
  int wid  = (blockIdx.x << 2) + (threadIdx.x >> 6);  // 0..4095
  int lane = threadIdx.x & 63;
  int c = wid >> 6, e = wid & 63;
  double wpe = (double)Wp[e];
  const double* sp = statT + c * BW_N;
  double s = 0.0;
#pragma unroll
  for (int k = 0; k < 16; ++k) s += tanh(sp[lane + (k << 6)] * wpe);
#pragma unroll
  for (int off = 32; off; off >>= 1) s += __shfl_down(s, off, 64);
  if (lane == 0) Z[c * 64 + e] = s * (1.0 / 1024.0);
}

// ---------------------------------------------------------------------------
// K3: single-block graph construction: D2, 2 refine steps, exact JAX threefry
// (PARTITIONABLE scheme — default since JAX 0.4.30) gumbel top-k, sym degree
// norm, outputs A_final (fp32) and A2 = A*A (fp32).
// All in fp64 to track the numpy reference through the hard top-k selection.
// ---------------------------------------------------------------------------
__device__ __forceinline__ unsigned rotl32(unsigned v, unsigned d) {
  return (v << d) | (v >> (32u - d));
}

// JAX partitionable threefry2x32-20, key = (0, 42).
// Element m: counter = uint64(m) -> (hi, lo) = (0, m); inputs
// x0 = hi + k0, x1 = lo + k1; output = x0_out ^ x1_out.
__device__ __forceinline__ unsigned threefry_bits(unsigned m) {
  const unsigned k0 = 0u, k1 = 42u, k2 = 0x1BD11BDAu ^ k0 ^ k1;
  unsigned x0 = 0u + k0;   // counts_hi + k0
  unsigned x1 = m + k1;    // counts_lo + k1
#define TF_R4(a,b,c,d) \
  x0 += x1; x1 = rotl32(x1,a); x1 ^= x0; \
  x0 += x1; x1 = rotl32(x1,b); x1 ^= x0; \
  x0 += x1; x1 = rotl32(x1,c); x1 ^= x0; \
  x0 += x1; x1 = rotl32(x1,d); x1 ^= x0;
  TF_R4(13,15,26,6)  x0 += k1; x1 += k2 + 1u;
  TF_R4(17,29,16,24) x0 += k2; x1 += k0 + 2u;
  TF_R4(13,15,26,6)  x0 += k0; x1 += k1 + 3u;
  TF_R4(17,29,16,24) x0 += k1; x1 += k2 + 4u;
  TF_R4(13,15,26,6)  x0 += k2; x1 += k0 + 5u;
#undef TF_R4
  return x0 ^ x1;
}

__device__ __forceinline__ double softplus_d(double x) {
  return (x > 0.0) ? x + log1p(exp(-x)) : log1p(exp(x));
}

__global__ __launch_bounds__(1024) void k_graph(
    const double* __restrict__ Z,
    const float* __restrict__ w1, const float* __restrict__ b1,
    const float* __restrict__ w2, const float* __restrict__ b2,
    const float* __restrict__ beta_p, const float* __restrict__ gres_p,
    const float* __restrict__ temp_p,
    float* __restrict__ Aout, float* __restrict__ A2out) {
  __shared__ double As[64 * 65];   // Z, then A (stride-65 padded)
  __shared__ float  Af[64 * 65];   // A_final in fp32 for the A2 matmul
  __shared__ double sq[64];
  __shared__ double dinv[64];

  int tid  = threadIdx.x;
  int i_   = tid >> 4;           // 0..63
  int j0   = (tid & 15) << 2;    // 0,4,...,60  (thread owns entries (i_, j0..j0+3))
  int wv   = tid >> 6;           // wave 0..15
  int lane = tid & 63;

  // stage Z into padded LDS
#pragma unroll
  for (int u = 0; u < 4; ++u) As[AIDX(i_, j0 + u)] = Z[(i_ << 6) + j0 + u];
  __syncthreads();

  if (tid < 64) {
    double s = 0.0;
    for (int e = 0; e < 64; ++e) { double z = As[AIDX(tid, e)]; s += z * z; }
    sq[tid] = s;
  }
  __syncthreads();

  // D2 into registers (kept for both refine steps)
  double d2r[4];
  {
    double dot[4] = {0.0, 0.0, 0.0, 0.0};
    for (int e = 0; e < 64; ++e) {
      double zi = As[AIDX(i_, e)];
#pragma unroll
      for (int u = 0; u < 4; ++u) dot[u] += zi * As[AIDX(j0 + u, e)];
    }
#pragma unroll
    for (int u = 0; u < 4; ++u) {
      double v = sq[i_] + sq[j0 + u] - 2.0 * dot[u];
      d2r[u] = (v > 0.0 ? v : 0.0) * 0.5;
    }
  }
  __syncthreads();

  // A = I
#pragma unroll
  for (int u = 0; u < 4; ++u) As[AIDX(i_, j0 + u)] = (i_ == j0 + u) ? 1.0 : 0.0;
  __syncthreads();

  double beta = (double)beta_p[0], gres = (double)gres_p[0];
  double temp = (double)temp_p[0];
  double tclip = temp > 1e-6 ? temp : 1e-6;
  double b2d = (double)b2[0];
  const double inv_sqrt2 = 0.70710678118654752440;

  // two refinement steps
  for (int step = 0; step < 2; ++step) {
    double nv[4];
#pragma unroll
    for (int u = 0; u < 4; ++u) {
      double a = As[AIDX(i_, j0 + u)] - 0.2 * d2r[u];
      double acc = b2d;
#pragma unroll
      for (int k = 0; k < 16; ++k) {
        double zz = a * (double)w1[k] + (double)b1[k];
        double h  = 0.5 * zz * (1.0 + erf(zz * inv_sqrt2));
        acc += h * (double)w2[k];
      }
      nv[u] = a + beta * (softplus_d(acc) * gres);
    }
#pragma unroll
    for (int u = 0; u < 4; ++u) As[AIDX(i_, j0 + u)] = nv[u];
    __syncthreads();
    // sym, relu, +I
#pragma unroll
    for (int u = 0; u < 4; ++u)
      nv[u] = 0.5 * (As[AIDX(i_, j0 + u)] + As[AIDX(j0 + u, i_)]);
    __syncthreads();
#pragma unroll
    for (int u = 0; u < 4; ++u) {
      double v = nv[u] > 0.0 ? nv[u] : 0.0;
      if (i_ == j0 + u) v += 1.0;
      As[AIDX(i_, j0 + u)] = v;
    }
    __syncthreads();
  }

  // Gumbel top-k mask (wave wv owns rows 4wv..4wv+3; lane = column)
  double maskedv[4];
#pragma unroll
  for (int rr = 0; rr < 4; ++rr) {
    int r = (wv << 2) + rr;
    unsigned m = (unsigned)((r << 6) + lane);
    unsigned bits = threefry_bits(m);
    float uf = __uint_as_float((bits >> 9) | 0x3f800000u) - 1.0f;
    if (uf == 0.0f) uf = 1.17549435e-38f;            // minval = finfo(f32).tiny
    float gf = -logf(-logf(uf));                     // fp32, as JAX computes it
    double g = (double)gf;
    double aval = As[AIDX(r, lane)];
    double val  = (aval + g) / tclip;
    bool keep = false;
    for (int it = 0; it < 16; ++it) {
      double bv = val; int bi = lane;
#pragma unroll
      for (int off = 32; off; off >>= 1) {
        double ov = __shfl_xor(bv, off, 64);
        int    oi = __shfl_xor(bi, off, 64);
        if (ov > bv || (ov == bv && oi < bi)) { bv = ov; bi = oi; }
      }
      if (lane == bi) { keep = true; val = -1e300; }
    }
    maskedv[rr] = keep ? aval : 0.0;
  }
  __syncthreads();
#pragma unroll
  for (int rr = 0; rr < 4; ++rr) As[AIDX((wv << 2) + rr, lane)] = maskedv[rr];
  __syncthreads();

  // A = relu(0.5*(A+A^T)) + I
  {
    double nv[4];
#pragma unroll
    for (int u = 0; u < 4; ++u)
      nv[u] = 0.5 * (As[AIDX(i_, j0 + u)] + As[AIDX(j0 + u, i_)]);
    __syncthreads();
#pragma unroll
    for (int u = 0; u < 4; ++u) {
      double v = nv[u] > 0.0 ? nv[u] : 0.0;
      if (i_ == j0 + u) v += 1.0;
      As[AIDX(i_, j0 + u)] = v;
    }
    __syncthreads();
  }

  // degree normalization
#pragma unroll
  for (int rr = 0; rr < 4; ++rr) {
    int r = (wv << 2) + rr;
    double s = As[AIDX(r, lane)];
#pragma unroll
    for (int off = 32; off; off >>= 1) s += __shfl_xor(s, off, 64);
    if (lane == 0) { double cs = s > 1e-6 ? s : 1e-6; dinv[r] = 1.0 / sqrt(cs); }
  }
  __syncthreads();

  // A_final = dinv_i * A * dinv_j + I ; emit fp32 copies
#pragma unroll
  for (int u = 0; u < 4; ++u) {
    double v = dinv[i_] * As[AIDX(i_, j0 + u)] * dinv[j0 + u];
    if (i_ == j0 + u) v += 1.0;
    float vf = (float)v;
    Af[AIDX(i_, j0 + u)] = vf;
    Aout[(i_ << 6) + j0 + u] = vf;
  }
  __syncthreads();

  // A2 = A_final @ A_final  (fp32 — feeds the fp32 propagation)
  {
    float acc[4] = {0.f, 0.f, 0.f, 0.f};
    for (int k = 0; k < 64; ++k) {
      float aik = Af[AIDX(i_, k)];
#pragma unroll
      for (int u = 0; u < 4; ++u) acc[u] += aik * Af[AIDX(k, j0 + u)];
    }
#pragma unroll
    for (int u = 0; u < 4; ++u) A2out[(i_ << 6) + j0 + u] = acc[u];
  }
}

// ---------------------------------------------------------------------------
// K4: out[b,c,w*T+t] = sum_j A2[c,j] * x[b,w,j,t]
// lane = t; xv[64] in VGPRs (coalesced).  A2 rows are pulled through the
// TRUE scalar-memory path: inline-asm s_load_dwordx16 into SGPRs, so each
// v_fmac_f32 reads its A2 coefficient as an SGPR operand (1 SGPR read per
// VALU instr is architecturally free).  This removes the ~4096 per-wave
// broadcast VMEM loads the compiler emits when it cannot prove the uniform
// global loads invariant.
// ---------------------------------------------------------------------------
typedef __attribute__((ext_vector_type(16))) float f32x16;

__global__ __launch_bounds__(256) void k_prop(const float* __restrict__ x,
                                              const float* __restrict__ A2,
                                              float* __restrict__ out) {
  int bw   = blockIdx.x >> 2;          // 0..1023  (= b*16 + w)
  int tq   = blockIdx.x & 3;
  int wv   = threadIdx.x >> 6;
  int lane = threadIdx.x & 63;
  int t0   = (tq << 8) + (wv << 6);    // 0,64,...,960

  const float* xp = x + ((size_t)bw << 16) + (size_t)(t0 + lane);
  float xv[64];
#pragma unroll
  for (int j = 0; j < 64; ++j) xv[j] = xp[(size_t)j << 10];

  int b = bw >> 4, w = bw & 15;
  float* op = out + ((size_t)b << 20) + (size_t)(w << 10) + (size_t)(t0 + lane);

  // 16 FMAs from one SGPR row-quarter; accumulation split (a0..a3 by j&3)
  // kept identical to the previously-verified kernel for bit-stable numerics.
#define FMA16(R, OFS) \
  _Pragma("unroll") \
  for (int j = 0; j < 16; j += 4) { \
    a0 = fmaf(R[j    ], xv[(OFS) + j    ], a0); \
    a1 = fmaf(R[j + 1], xv[(OFS) + j + 1], a1); \
    a2 = fmaf(R[j + 2], xv[(OFS) + j + 2], a2); \
    a3 = fmaf(R[j + 3], xv[(OFS) + j + 3], a3); \
  }

#pragma unroll 1
  for (int c = 0; c < 64; ++c) {
    f32x16 r0, r1, r2, r3;
    unsigned coff = (unsigned)(c << 8);    // c * 64 floats * 4 B
    asm volatile(
      "s_load_dwordx16 %0, %4, %5 offset:0x0\n\t"
      "s_load_dwordx16 %1, %4, %5 offset:0x40\n\t"
      "s_load_dwordx16 %2, %4, %5 offset:0x80\n\t"
      "s_load_dwordx16 %3, %4, %5 offset:0xc0\n\t"
      "s_waitcnt lgkmcnt(0)"
      : "=s"(r0), "=s"(r1), "=s"(r2), "=s"(r3)
      : "s"(A2), "s"(coff));
    float a0 = 0.f, a1 = 0.f, a2 = 0.f, a3 = 0.f;
    FMA16(r0, 0)
    FMA16(r1, 16)
    FMA16(r2, 32)
    FMA16(r3, 48)
    op[(size_t)c << 14] = (a0 + a1) + (a2 + a3);
  }
#undef FMA16
}

// ---------------------------------------------------------------------------
extern "C" void kernel_launch(void* const* d_in, const int* in_sizes, int n_in,
                              void* d_out, int out_size, void* d_ws, size_t ws_size,
                              hipStream_t stream) {
  const float* x    = (const float*)d_in[0];
  const float* Wp   = (const float*)d_in[1];
  const float* w1   = (const float*)d_in[2];
  const float* b1   = (const float*)d_in[3];
  const float* w2   = (const float*)d_in[4];
  const float* b2   = (const float*)d_in[5];
  const float* beta = (const float*)d_in[6];
  const float* gres = (const float*)d_in[7];
  const float* temp = (const float*)d_in[8];

  // workspace layout
  double* statT = (double*)d_ws;                                    // 512 KB
  double* Z     = (double*)((char*)d_ws + (512 << 10));             // 32 KB
  float*  A2    = (float*)((char*)d_ws + (512 << 10) + (32 << 10)); // 16 KB

  float* out  = (float*)d_out;
  float* Aout = out + (size_t)B_N * C_N * W_N * T_N;                // 67108864

  k_stats<<<16384, 256, 0, stream>>>(x, statT);
  k_embed<<<1024, 256, 0, stream>>>(statT, Wp, Z);
  k_graph<<<1, 1024, 0, stream>>>(Z, w1, b1, w2, b2, beta, gres, temp, Aout, A2);
  k_prop<<<4096, 256, 0, stream>>>(x, A2, out);
}

// Round 8
// 796.018 us; speedup vs baseline: 1.4097x; 1.4097x over previous
//
#include <hip/hip_runtime.h>
#include <cmath>
#include <cstdint>

// Problem constants
#define B_N  64
#define W_N  16
#define C_N  64
#define T_N  1024
#define BW_N 1024           // B*W
#define DE_N 64
#define AIDX(i,j) ((i)*65 + (j))   // +1 pad (stride 65) to break stride-64 LDS bank conflicts

// ---------------------------------------------------------------------------
// K1: per-(b,w,c) stats over T.  One wave per row of 1024 floats.
// stat = 0.5*(mean + energy), accumulated in fp64, stored transposed [C][BW].
// ---------------------------------------------------------------------------
__global__ __launch_bounds__(256) void k_stats(const float* __restrict__ x,
                                               double* __restrict__ statT) {
  int wid  = (blockIdx.x << 2) + (threadIdx.x >> 6);  // row id = bw*64 + c, 0..65535
  int lane = threadIdx.x & 63;
  const float4* xp = (const float4*)(x + (size_t)wid * T_N);
  double s = 0.0, q = 0.0;
#pragma unroll
  for (int k = 0; k < 4; ++k) {
    float4 v = xp[lane + (k << 6)];
    double a0 = v.x, a1 = v.y, a2 = v.z, a3 = v.w;
    s += (a0 + a1) + (a2 + a3);
    q += (a0*a0 + a1*a1) + (a2*a2 + a3*a3);
  }
#pragma unroll
  for (int off = 32; off; off >>= 1) {
    s += __shfl_down(s, off, 64);
    q += __shfl_down(q, off, 64);
  }
  if (lane == 0) {
    int bw = wid >> 6, c = wid & 63;
    statT[c * BW_N + bw] = 0.5 * (s * (1.0 / T_N) + q * (1.0 / T_N));
  }
}

// ---------------------------------------------------------------------------
// K2: Z[c][e] = mean_{bw} tanh(stat[bw][c] * Wp[e]).  One wave per (c,e).
// tanh in fp32 (the reference computes this entire path in fp32).
// Mean accumulation stays fp64.
// ---------------------------------------------------------------------------
__global__ __launch_bounds__(256) void k_embed(const double* __restrict__ statT,
                                               const float* __restrict__ Wp,
                                               double* __restrict__ Z) {
  int wid  = (blockIdx.x << 2) + (threadIdx.x >> 6);  // 0..4095
  int lane = threadIdx.x & 63;
  int c = wid >> 6, e = wid & 63;
  float wpe = Wp[e];
  const double* sp = statT + c * BW_N;
  double s = 0.0;
#pragma unroll
  for (int k = 0; k < 16; ++k) s += (double)tanhf((float)sp[lane + (k << 6)] * wpe);
#pragma unroll
  for (int off = 32; off; off >>= 1) s += __shfl_down(s, off, 64);
  if (lane == 0) Z[c * 64 + e] = s * (1.0 / 1024.0);
}

// ---------------------------------------------------------------------------
// K3: single-block graph construction: D2, 2 refine steps, exact JAX threefry
// (PARTITIONABLE scheme) gumbel top-k, sym degree norm, outputs A_final
// (fp32) and A2 = A*A (fp32).  Matrix bookkeeping fp64; refine MLP fp32.
// ---------------------------------------------------------------------------
__device__ __forceinline__ unsigned rotl32(unsigned v, unsigned d) {
  return (v << d) | (v >> (32u - d));
}

__device__ __forceinline__ unsigned threefry_bits(unsigned m) {
  const unsigned k0 = 0u, k1 = 42u, k2 = 0x1BD11BDAu ^ k0 ^ k1;
  unsigned x0 = 0u + k0;   // counts_hi + k0
  unsigned x1 = m + k1;    // counts_lo + k1
#define TF_R4(a,b,c,d) \
  x0 += x1; x1 = rotl32(x1,a); x1 ^= x0; \
  x0 += x1; x1 = rotl32(x1,b); x1 ^= x0; \
  x0 += x1; x1 = rotl32(x1,c); x1 ^= x0; \
  x0 += x1; x1 = rotl32(x1,d); x1 ^= x0;
  TF_R4(13,15,26,6)  x0 += k1; x1 += k2 + 1u;
  TF_R4(17,29,16,24) x0 += k2; x1 += k0 + 2u;
  TF_R4(13,15,26,6)  x0 += k0; x1 += k1 + 3u;
  TF_R4(17,29,16,24) x0 += k1; x1 += k2 + 4u;
  TF_R4(13,15,26,6)  x0 += k2; x1 += k0 + 5u;
#undef TF_R4
  return x0 ^ x1;
}

__device__ __forceinline__ float softplus_f(float x) {
  return (x > 0.f) ? x + log1pf(expf(-x)) : log1pf(expf(x));
}

__global__ __launch_bounds__(1024) void k_graph(
    const double* __restrict__ Z,
    const float* __restrict__ w1, const float* __restrict__ b1,
    const float* __restrict__ w2, const float* __restrict__ b2,
    const float* __restrict__ beta_p, const float* __restrict__ gres_p,
    const float* __restrict__ temp_p,
    float* __restrict__ Aout, float* __restrict__ A2out) {
  __shared__ double As[64 * 65];   // Z, then A (stride-65 padded)
  __shared__ float  Af[64 * 65];   // A_final in fp32 for the A2 matmul
  __shared__ double sq[64];
  __shared__ double dinv[64];

  int tid  = threadIdx.x;
  int i_   = tid >> 4;           // 0..63
  int j0   = (tid & 15) << 2;    // 0,4,...,60  (thread owns entries (i_, j0..j0+3))
  int wv   = tid >> 6;           // wave 0..15
  int lane = tid & 63;

  // stage Z into padded LDS
#pragma unroll
  for (int u = 0; u < 4; ++u) As[AIDX(i_, j0 + u)] = Z[(i_ << 6) + j0 + u];
  __syncthreads();

  if (tid < 64) {
    double s = 0.0;
    for (int e = 0; e < 64; ++e) { double z = As[AIDX(tid, e)]; s += z * z; }
    sq[tid] = s;
  }
  __syncthreads();

  // D2 into registers (kept for both refine steps)
  double d2r[4];
  {
    double dot[4] = {0.0, 0.0, 0.0, 0.0};
    for (int e = 0; e < 64; ++e) {
      double zi = As[AIDX(i_, e)];
#pragma unroll
      for (int u = 0; u < 4; ++u) dot[u] += zi * As[AIDX(j0 + u, e)];
    }
#pragma unroll
    for (int u = 0; u < 4; ++u) {
      double v = sq[i_] + sq[j0 + u] - 2.0 * dot[u];
      d2r[u] = (v > 0.0 ? v : 0.0) * 0.5;
    }
  }
  __syncthreads();

  // A = I
#pragma unroll
  for (int u = 0; u < 4; ++u) As[AIDX(i_, j0 + u)] = (i_ == j0 + u) ? 1.0 : 0.0;
  __syncthreads();

  double beta = (double)beta_p[0], gres = (double)gres_p[0];
  double temp = (double)temp_p[0];
  double tclip = temp > 1e-6 ? temp : 1e-6;

  // MLP weights in fp32 registers (they are fp32 inputs anyway)
  float w1r[16], b1r[16], w2r[16];
#pragma unroll
  for (int k = 0; k < 16; ++k) { w1r[k] = w1[k]; b1r[k] = b1[k]; w2r[k] = w2[k]; }
  float b2f = b2[0];
  const float inv_sqrt2f = 0.70710678118654752440f;

  // two refinement steps — MLP in fp32 (the transcendental hot spot)
  for (int step = 0; step < 2; ++step) {
    double nv[4];
#pragma unroll
    for (int u = 0; u < 4; ++u) {
      double a = As[AIDX(i_, j0 + u)] - 0.2 * d2r[u];
      float af = (float)a;
      float acc = b2f;
#pragma unroll
      for (int k = 0; k < 16; ++k) {
        float zz = fmaf(af, w1r[k], b1r[k]);
        float h  = 0.5f * zz * (1.0f + erff(zz * inv_sqrt2f));
        acc = fmaf(h, w2r[k], acc);
      }
      nv[u] = a + beta * ((double)softplus_f(acc) * gres);
    }
#pragma unroll
    for (int u = 0; u < 4; ++u) As[AIDX(i_, j0 + u)] = nv[u];
    __syncthreads();
    // sym, relu, +I
#pragma unroll
    for (int u = 0; u < 4; ++u)
      nv[u] = 0.5 * (As[AIDX(i_, j0 + u)] + As[AIDX(j0 + u, i_)]);
    __syncthreads();
#pragma unroll
    for (int u = 0; u < 4; ++u) {
      double v = nv[u] > 0.0 ? nv[u] : 0.0;
      if (i_ == j0 + u) v += 1.0;
      As[AIDX(i_, j0 + u)] = v;
    }
    __syncthreads();
  }

  // Gumbel top-k mask (wave wv owns rows 4wv..4wv+3; lane = column)
  double maskedv[4];
#pragma unroll
  for (int rr = 0; rr < 4; ++rr) {
    int r = (wv << 2) + rr;
    unsigned m = (unsigned)((r << 6) + lane);
    unsigned bits = threefry_bits(m);
    float uf = __uint_as_float((bits >> 9) | 0x3f800000u) - 1.0f;
    if (uf == 0.0f) uf = 1.17549435e-38f;            // minval = finfo(f32).tiny
    float gf = -logf(-logf(uf));                     // fp32, as JAX computes it
    double g = (double)gf;
    double aval = As[AIDX(r, lane)];
    double val  = (aval + g) / tclip;
    bool keep = false;
    for (int it = 0; it < 16; ++it) {
      double bv = val; int bi = lane;
#pragma unroll
      for (int off = 32; off; off >>= 1) {
        double ov = __shfl_xor(bv, off, 64);
        int    oi = __shfl_xor(bi, off, 64);
        if (ov > bv || (ov == bv && oi < bi)) { bv = ov; bi = oi; }
      }
      if (lane == bi) { keep = true; val = -1e300; }
    }
    maskedv[rr] = keep ? aval : 0.0;
  }
  __syncthreads();
#pragma unroll
  for (int rr = 0; rr < 4; ++rr) As[AIDX((wv << 2) + rr, lane)] = maskedv[rr];
  __syncthreads();

  // A = relu(0.5*(A+A^T)) + I
  {
    double nv[4];
#pragma unroll
    for (int u = 0; u < 4; ++u)
      nv[u] = 0.5 * (As[AIDX(i_, j0 + u)] + As[AIDX(j0 + u, i_)]);
    __syncthreads();
#pragma unroll
    for (int u = 0; u < 4; ++u) {
      double v = nv[u] > 0.0 ? nv[u] : 0.0;
      if (i_ == j0 + u) v += 1.0;
      As[AIDX(i_, j0 + u)] = v;
    }
    __syncthreads();
  }

  // degree normalization
#pragma unroll
  for (int rr = 0; rr < 4; ++rr) {
    int r = (wv << 2) + rr;
    double s = As[AIDX(r, lane)];
#pragma unroll
    for (int off = 32; off; off >>= 1) s += __shfl_xor(s, off, 64);
    if (lane == 0) { double cs = s > 1e-6 ? s : 1e-6; dinv[r] = 1.0 / sqrt(cs); }
  }
  __syncthreads();

  // A_final = dinv_i * A * dinv_j + I ; emit fp32 copies
#pragma unroll
  for (int u = 0; u < 4; ++u) {
    double v = dinv[i_] * As[AIDX(i_, j0 + u)] * dinv[j0 + u];
    if (i_ == j0 + u) v += 1.0;
    float vf = (float)v;
    Af[AIDX(i_, j0 + u)] = vf;
    Aout[(i_ << 6) + j0 + u] = vf;
  }
  __syncthreads();

  // A2 = A_final @ A_final  (fp32 — feeds the fp32 propagation)
  {
    float acc[4] = {0.f, 0.f, 0.f, 0.f};
    for (int k = 0; k < 64; ++k) {
      float aik = Af[AIDX(i_, k)];
#pragma unroll
      for (int u = 0; u < 4; ++u) acc[u] += aik * Af[AIDX(k, j0 + u)];
    }
#pragma unroll
    for (int u = 0; u < 4; ++u) A2out[(i_ << 6) + j0 + u] = acc[u];
  }
}

// ---------------------------------------------------------------------------
// K4: out[b,c,w*T+t] = sum_j A2[c,j] * x[b,w,j,t]
// lane = t; xv[64] in VGPRs (coalesced).  A2 rows via scalar memory,
// software-pipelined at half-row (32-float) granularity: every
// s_waitcnt lgkmcnt(0) has ~32 FMAs of independent work issued ahead of it.
// Ordering enforced by the documented pattern: volatile asm (keeps program
// order among asms) + __builtin_amdgcn_sched_barrier(0) right after each
// waitcnt (stops register-only FMAs hoisting above the wait — rule #18).
// The post-loop s_waitcnt drains the final dead prefetch: a wave must NOT
// reach s_endpgm with an SMEM load in flight (SGPR writeback would land
// after register deallocation → corrupts co-resident waves).
// Stores are nontemporal (streaming) to avoid write-allocate HBM fetches.
// ---------------------------------------------------------------------------
typedef __attribute__((ext_vector_type(16))) float f32x16;

__global__ __launch_bounds__(256) void k_prop(const float* __restrict__ x,
                                              const float* __restrict__ A2,
                                              float* __restrict__ out) {
  int bw   = blockIdx.x >> 2;          // 0..1023  (= b*16 + w)
  int tq   = blockIdx.x & 3;
  int wv   = threadIdx.x >> 6;
  int lane = threadIdx.x & 63;
  int t0   = (tq << 8) + (wv << 6);    // 0,64,...,960

  const float* xp = x + ((size_t)bw << 16) + (size_t)(t0 + lane);
  float xv[64];
#pragma unroll
  for (int j = 0; j < 64; ++j) xv[j] = xp[(size_t)j << 10];

  int b = bw >> 4, w = bw & 15;
  float* op = out + ((size_t)b << 20) + (size_t)(w << 10) + (size_t)(t0 + lane);

  // 16 FMAs from one SGPR half-row-chunk; accumulation split (a0..a3 by j&3)
  // and j-ascending order kept identical to the verified kernel.
#define FMA16(R, OFS) \
  _Pragma("unroll") \
  for (int j = 0; j < 16; j += 4) { \
    a0 = fmaf(R[j    ], xv[(OFS) + j    ], a0); \
    a1 = fmaf(R[j + 1], xv[(OFS) + j + 1], a1); \
    a2 = fmaf(R[j + 2], xv[(OFS) + j + 2], a2); \
    a3 = fmaf(R[j + 3], xv[(OFS) + j + 3], a3); \
  }

  f32x16 h0a, h0b, h1a, h1b;
  {
    unsigned z = 0u;
    // prologue: issue first half of row 0
    asm volatile(
      "s_load_dwordx16 %0, %2, %3 offset:0x0\n\t"
      "s_load_dwordx16 %1, %2, %3 offset:0x40"
      : "=s"(h0a), "=s"(h0b) : "s"(A2), "s"(z));
  }

#pragma unroll 1
  for (int c = 0; c < 64; ++c) {
    unsigned coff  = (unsigned)(c << 8);                    // c * 256 B
    unsigned cnoff = (unsigned)((c < 63 ? c + 1 : 63) << 8); // clamped: no OOB prefetch
    float a0 = 0.f, a1 = 0.f, a2 = 0.f, a3 = 0.f;
    // wait for current row's first half (issued last iteration / prologue)
    asm volatile("s_waitcnt lgkmcnt(0)");
    __builtin_amdgcn_sched_barrier(0);
    // issue current row's second half (volatile: stays after the wait)
    asm volatile(
      "s_load_dwordx16 %0, %2, %3 offset:0x80\n\t"
      "s_load_dwordx16 %1, %2, %3 offset:0xc0"
      : "=s"(h1a), "=s"(h1b) : "s"(A2), "s"(coff));
    FMA16(h0a, 0)
    FMA16(h0b, 16)
    asm volatile("s_waitcnt lgkmcnt(0)");
    __builtin_amdgcn_sched_barrier(0);
    // issue next row's first half; overlaps with second-half FMAs
    asm volatile(
      "s_load_dwordx16 %0, %2, %3 offset:0x0\n\t"
      "s_load_dwordx16 %1, %2, %3 offset:0x40"
      : "=s"(h0a), "=s"(h0b) : "s"(A2), "s"(cnoff));
    FMA16(h1a, 32)
    FMA16(h1b, 48)
    float r = (a0 + a1) + (a2 + a3);
    __builtin_nontemporal_store(r, op + ((size_t)c << 14));
  }
#undef FMA16
  // drain the final (dead) prefetch before s_endpgm — pending SMEM writeback
  // after SGPR dealloc corrupts other waves.
  asm volatile("s_waitcnt lgkmcnt(0)");
}

// ---------------------------------------------------------------------------
extern "C" void kernel_launch(void* const* d_in, const int* in_sizes, int n_in,
                              void* d_out, int out_size, void* d_ws, size_t ws_size,
                              hipStream_t stream) {
  const float* x    = (const float*)d_in[0];
  const float* Wp   = (const float*)d_in[1];
  const float* w1   = (const float*)d_in[2];
  const float* b1   = (const float*)d_in[3];
  const float* w2   = (const float*)d_in[4];
  const float* b2   = (const float*)d_in[5];
  const float* beta = (const float*)d_in[6];
  const float* gres = (const float*)d_in[7];
  const float* temp = (const float*)d_in[8];

  // workspace layout
  double* statT = (double*)d_ws;                                    // 512 KB
  double* Z     = (double*)((char*)d_ws + (512 << 10));             // 32 KB
  float*  A2    = (float*)((char*)d_ws + (512 << 10) + (32 << 10)); // 16 KB

  float* out  = (float*)d_out;
  float* Aout = out + (size_t)B_N * C_N * W_N * T_N;                // 67108864

  k_stats<<<16384, 256, 0, stream>>>(x, statT);
  k_embed<<<1024, 256, 0, stream>>>(statT, Wp, Z);
  k_graph<<<1, 1024, 0, stream>>>(Z, w1, b1, w2, b2, beta, gres, temp, Aout, A2);
  k_prop<<<4096, 256, 0, stream>>>(x, A2, out);
}

// Round 14
// 697.908 us; speedup vs baseline: 1.6078x; 1.1406x over previous
//
#include <hip/hip_runtime.h>
#include <cmath>
#include <cstdint>

// Problem constants
#define B_N  64
#define W_N  16
#define C_N  64
#define T_N  1024
#define BW_N 1024           // B*W
#define DE_N 64
#define AIDX(i,j) ((i)*65 + (j))   // +1 pad (stride 65) to break stride-64 LDS bank conflicts

// ---------------------------------------------------------------------------
// K1: per-(b,w,c) stats over T.  One wave per row of 1024 floats.
// stat = 0.5*(mean + energy), accumulated in fp64, stored transposed [C][BW].
// ---------------------------------------------------------------------------
__global__ __launch_bounds__(256) void k_stats(const float* __restrict__ x,
                                               double* __restrict__ statT) {
  int wid  = (blockIdx.x << 2) + (threadIdx.x >> 6);  // row id = bw*64 + c, 0..65535
  int lane = threadIdx.x & 63;
  const float4* xp = (const float4*)(x + (size_t)wid * T_N);
  double s = 0.0, q = 0.0;
#pragma unroll
  for (int k = 0; k < 4; ++k) {
    float4 v = xp[lane + (k << 6)];
    double a0 = v.x, a1 = v.y, a2 = v.z, a3 = v.w;
    s += (a0 + a1) + (a2 + a3);
    q += (a0*a0 + a1*a1) + (a2*a2 + a3*a3);
  }
#pragma unroll
  for (int off = 32; off; off >>= 1) {
    s += __shfl_down(s, off, 64);
    q += __shfl_down(q, off, 64);
  }
  if (lane == 0) {
    int bw = wid >> 6, c = wid & 63;
    statT[c * BW_N + bw] = 0.5 * (s * (1.0 / T_N) + q * (1.0 / T_N));
  }
}

// ---------------------------------------------------------------------------
// K2: Z[c][e] = mean_{bw} tanh(stat[bw][c] * Wp[e]).  One wave per (c,e).
// tanh in fp32 (the reference computes this entire path in fp32).
// Mean accumulation stays fp64.
// ---------------------------------------------------------------------------
__global__ __launch_bounds__(256) void k_embed(const double* __restrict__ statT,
                                               const float* __restrict__ Wp,
                                               double* __restrict__ Z) {
  int wid  = (blockIdx.x << 2) + (threadIdx.x >> 6);  // 0..4095
  int lane = threadIdx.x & 63;
  int c = wid >> 6, e = wid & 63;
  float wpe = Wp[e];
  const double* sp = statT + c * BW_N;
  double s = 0.0;
#pragma unroll
  for (int k = 0; k < 16; ++k) s += (double)tanhf((float)sp[lane + (k << 6)] * wpe);
#pragma unroll
  for (int off = 32; off; off >>= 1) s += __shfl_down(s, off, 64);
  if (lane == 0) Z[c * 64 + e] = s * (1.0 / 1024.0);
}

// ---------------------------------------------------------------------------
// K3: single-block graph construction: D2, 2 refine steps, exact JAX threefry
// (PARTITIONABLE scheme) gumbel top-k, sym degree norm, outputs A_final
// (fp32) and A2 = A*A (fp32).  Matrix bookkeeping fp64; refine MLP fp32.
//
// __launch_bounds__(1024, 4): this kernel is ONE 1024-thread block = 4
// waves/SIMD, 1 block/CU — declaring that raises the VGPR budget to 128
// (the R8 build chose VGPR=48 optimizing for impossible occupancy, which
// spilled the MLP chains to scratch: 98 -> 257 us, rule #19/#20).
// MLP loop is k-outer / u-inner so 4-wide ILP is structural, concurrent
// erff chains capped at 4 (low register pressure), weight indices
// compile-time-constant.  Per-acc[u] op order unchanged -> bit-identical.
// ---------------------------------------------------------------------------
__device__ __forceinline__ unsigned rotl32(unsigned v, unsigned d) {
  return (v << d) | (v >> (32u - d));
}

__device__ __forceinline__ unsigned threefry_bits(unsigned m) {
  const unsigned k0 = 0u, k1 = 42u, k2 = 0x1BD11BDAu ^ k0 ^ k1;
  unsigned x0 = 0u + k0;   // counts_hi + k0
  unsigned x1 = m + k1;    // counts_lo + k1
#define TF_R4(a,b,c,d) \
  x0 += x1; x1 = rotl32(x1,a); x1 ^= x0; \
  x0 += x1; x1 = rotl32(x1,b); x1 ^= x0; \
  x0 += x1; x1 = rotl32(x1,c); x1 ^= x0; \
  x0 += x1; x1 = rotl32(x1,d); x1 ^= x0;
  TF_R4(13,15,26,6)  x0 += k1; x1 += k2 + 1u;
  TF_R4(17,29,16,24) x0 += k2; x1 += k0 + 2u;
  TF_R4(13,15,26,6)  x0 += k0; x1 += k1 + 3u;
  TF_R4(17,29,16,24) x0 += k1; x1 += k2 + 4u;
  TF_R4(13,15,26,6)  x0 += k2; x1 += k0 + 5u;
#undef TF_R4
  return x0 ^ x1;
}

__device__ __forceinline__ float softplus_f(float x) {
  return (x > 0.f) ? x + log1pf(expf(-x)) : log1pf(expf(x));
}

__global__ __launch_bounds__(1024, 4) void k_graph(
    const double* __restrict__ Z,
    const float* __restrict__ w1, const float* __restrict__ b1,
    const float* __restrict__ w2, const float* __restrict__ b2,
    const float* __restrict__ beta_p, const float* __restrict__ gres_p,
    const float* __restrict__ temp_p,
    float* __restrict__ Aout, float* __restrict__ A2out) {
  __shared__ double As[64 * 65];   // Z, then A (stride-65 padded)
  __shared__ float  Af[64 * 65];   // A_final in fp32 for the A2 matmul
  __shared__ double sq[64];
  __shared__ double dinv[64];

  int tid  = threadIdx.x;
  int i_   = tid >> 4;           // 0..63
  int j0   = (tid & 15) << 2;    // 0,4,...,60  (thread owns entries (i_, j0..j0+3))
  int wv   = tid >> 6;           // wave 0..15
  int lane = tid & 63;

  // stage Z into padded LDS
#pragma unroll
  for (int u = 0; u < 4; ++u) As[AIDX(i_, j0 + u)] = Z[(i_ << 6) + j0 + u];
  __syncthreads();

  if (tid < 64) {
    double s = 0.0;
    for (int e = 0; e < 64; ++e) { double z = As[AIDX(tid, e)]; s += z * z; }
    sq[tid] = s;
  }
  __syncthreads();

  // D2 into registers (kept for both refine steps)
  double d2r[4];
  {
    double dot[4] = {0.0, 0.0, 0.0, 0.0};
    for (int e = 0; e < 64; ++e) {
      double zi = As[AIDX(i_, e)];
#pragma unroll
      for (int u = 0; u < 4; ++u) dot[u] += zi * As[AIDX(j0 + u, e)];
    }
#pragma unroll
    for (int u = 0; u < 4; ++u) {
      double v = sq[i_] + sq[j0 + u] - 2.0 * dot[u];
      d2r[u] = (v > 0.0 ? v : 0.0) * 0.5;
    }
  }
  __syncthreads();

  // A = I
#pragma unroll
  for (int u = 0; u < 4; ++u) As[AIDX(i_, j0 + u)] = (i_ == j0 + u) ? 1.0 : 0.0;
  __syncthreads();

  double beta = (double)beta_p[0], gres = (double)gres_p[0];
  double temp = (double)temp_p[0];
  double tclip = temp > 1e-6 ? temp : 1e-6;

  // MLP weights in fp32 registers (they are fp32 inputs anyway)
  float w1r[16], b1r[16], w2r[16];
#pragma unroll
  for (int k = 0; k < 16; ++k) { w1r[k] = w1[k]; b1r[k] = b1[k]; w2r[k] = w2[k]; }
  float b2f = b2[0];
  const float inv_sqrt2f = 0.70710678118654752440f;

  // two refinement steps — MLP in fp32, k-outer / u-inner (structural ILP=4)
  for (int step = 0; step < 2; ++step) {
    double av[4];
    float  af[4], acc[4];
#pragma unroll
    for (int u = 0; u < 4; ++u) {
      av[u]  = As[AIDX(i_, j0 + u)] - 0.2 * d2r[u];
      af[u]  = (float)av[u];
      acc[u] = b2f;
    }
#pragma unroll
    for (int k = 0; k < 16; ++k) {
      float zz[4], e4[4];
#pragma unroll
      for (int u = 0; u < 4; ++u) zz[u] = fmaf(af[u], w1r[k], b1r[k]);
#pragma unroll
      for (int u = 0; u < 4; ++u) e4[u] = erff(zz[u] * inv_sqrt2f);
#pragma unroll
      for (int u = 0; u < 4; ++u) {
        float h = 0.5f * zz[u] * (1.0f + e4[u]);
        acc[u] = fmaf(h, w2r[k], acc[u]);
      }
    }
    double nv[4];
#pragma unroll
    for (int u = 0; u < 4; ++u)
      nv[u] = av[u] + beta * ((double)softplus_f(acc[u]) * gres);
#pragma unroll
    for (int u = 0; u < 4; ++u) As[AIDX(i_, j0 + u)] = nv[u];
    __syncthreads();
    // sym, relu, +I
#pragma unroll
    for (int u = 0; u < 4; ++u)
      nv[u] = 0.5 * (As[AIDX(i_, j0 + u)] + As[AIDX(j0 + u, i_)]);
    __syncthreads();
#pragma unroll
    for (int u = 0; u < 4; ++u) {
      double v = nv[u] > 0.0 ? nv[u] : 0.0;
      if (i_ == j0 + u) v += 1.0;
      As[AIDX(i_, j0 + u)] = v;
    }
    __syncthreads();
  }

  // Gumbel top-k mask (wave wv owns rows 4wv..4wv+3; lane = column)
  double maskedv[4];
#pragma unroll
  for (int rr = 0; rr < 4; ++rr) {
    int r = (wv << 2) + rr;
    unsigned m = (unsigned)((r << 6) + lane);
    unsigned bits = threefry_bits(m);
    float uf = __uint_as_float((bits >> 9) | 0x3f800000u) - 1.0f;
    if (uf == 0.0f) uf = 1.17549435e-38f;            // minval = finfo(f32).tiny
    float gf = -logf(-logf(uf));                     // fp32, as JAX computes it
    double g = (double)gf;
    double aval = As[AIDX(r, lane)];
    double val  = (aval + g) / tclip;
    bool keep = false;
    for (int it = 0; it < 16; ++it) {
      double bv = val; int bi = lane;
#pragma unroll
      for (int off = 32; off; off >>= 1) {
        double ov = __shfl_xor(bv, off, 64);
        int    oi = __shfl_xor(bi, off, 64);
        if (ov > bv || (ov == bv && oi < bi)) { bv = ov; bi = oi; }
      }
      if (lane == bi) { keep = true; val = -1e300; }
    }
    maskedv[rr] = keep ? aval : 0.0;
  }
  __syncthreads();
#pragma unroll
  for (int rr = 0; rr < 4; ++rr) As[AIDX((wv << 2) + rr, lane)] = maskedv[rr];
  __syncthreads();

  // A = relu(0.5*(A+A^T)) + I
  {
    double nv[4];
#pragma unroll
    for (int u = 0; u < 4; ++u)
      nv[u] = 0.5 * (As[AIDX(i_, j0 + u)] + As[AIDX(j0 + u, i_)]);
    __syncthreads();
#pragma unroll
    for (int u = 0; u < 4; ++u) {
      double v = nv[u] > 0.0 ? nv[u] : 0.0;
      if (i_ == j0 + u) v += 1.0;
      As[AIDX(i_, j0 + u)] = v;
    }
    __syncthreads();
  }

  // degree normalization
#pragma unroll
  for (int rr = 0; rr < 4; ++rr) {
    int r = (wv << 2) + rr;
    double s = As[AIDX(r, lane)];
#pragma unroll
    for (int off = 32; off; off >>= 1) s += __shfl_xor(s, off, 64);
    if (lane == 0) { double cs = s > 1e-6 ? s : 1e-6; dinv[r] = 1.0 / sqrt(cs); }
  }
  __syncthreads();

  // A_final = dinv_i * A * dinv_j + I ; emit fp32 copies
#pragma unroll
  for (int u = 0; u < 4; ++u) {
    double v = dinv[i_] * As[AIDX(i_, j0 + u)] * dinv[j0 + u];
    if (i_ == j0 + u) v += 1.0;
    float vf = (float)v;
    Af[AIDX(i_, j0 + u)] = vf;
    Aout[(i_ << 6) + j0 + u] = vf;
  }
  __syncthreads();

  // A2 = A_final @ A_final  (fp32 — feeds the fp32 propagation)
  {
    float acc[4] = {0.f, 0.f, 0.f, 0.f};
    for (int k = 0; k < 64; ++k) {
      float aik = Af[AIDX(i_, k)];
#pragma unroll
      for (int u = 0; u < 4; ++u) acc[u] += aik * Af[AIDX(k, j0 + u)];
    }
#pragma unroll
    for (int u = 0; u < 4; ++u) A2out[(i_ << 6) + j0 + u] = acc[u];
  }
}

// ---------------------------------------------------------------------------
// K4: out[b,c,w*T+t] = sum_j A2[c,j] * x[b,w,j,t]
// lane = t; xv[64] in VGPRs (coalesced).  A2 rows via scalar memory,
// software-pipelined at half-row (32-float) granularity: every
// s_waitcnt lgkmcnt(0) has ~32 FMAs of independent work issued ahead of it.
// Ordering enforced by: volatile asm (program order among asms) +
// __builtin_amdgcn_sched_barrier(0) after each waitcnt (rule #18).
// Post-loop s_waitcnt drains the final dead prefetch (SMEM writeback after
// SGPR dealloc corrupts co-resident waves).  Nontemporal streaming stores.
// (This k_prop is HW-verified: R8 run passed with absmax 0.03125.)
// ---------------------------------------------------------------------------
typedef __attribute__((ext_vector_type(16))) float f32x16;

__global__ __launch_bounds__(256) void k_prop(const float* __restrict__ x,
                                              const float* __restrict__ A2,
                                              float* __restrict__ out) {
  int bw   = blockIdx.x >> 2;          // 0..1023  (= b*16 + w)
  int tq   = blockIdx.x & 3;
  int wv   = threadIdx.x >> 6;
  int lane = threadIdx.x & 63;
  int t0   = (tq << 8) + (wv << 6);    // 0,64,...,960

  const float* xp = x + ((size_t)bw << 16) + (size_t)(t0 + lane);
  float xv[64];
#pragma unroll
  for (int j = 0; j < 64; ++j) xv[j] = xp[(size_t)j << 10];

  int b = bw >> 4, w = bw & 15;
  float* op = out + ((size_t)b << 20) + (size_t)(w << 10) + (size_t)(t0 + lane);

  // 16 FMAs from one SGPR half-row-chunk; accumulation split (a0..a3 by j&3)
  // and j-ascending order kept identical to the verified kernel.
#define FMA16(R, OFS) \
  _Pragma("unroll") \
  for (int j = 0; j < 16; j += 4) { \
    a0 = fmaf(R[j    ], xv[(OFS) + j    ], a0); \
    a1 = fmaf(R[j + 1], xv[(OFS) + j + 1], a1); \
    a2 = fmaf(R[j + 2], xv[(OFS) + j + 2], a2); \
    a3 = fmaf(R[j + 3], xv[(OFS) + j + 3], a3); \
  }

  f32x16 h0a, h0b, h1a, h1b;
  {
    unsigned z = 0u;
    // prologue: issue first half of row 0
    asm volatile(
      "s_load_dwordx16 %0, %2, %3 offset:0x0\n\t"
      "s_load_dwordx16 %1, %2, %3 offset:0x40"
      : "=s"(h0a), "=s"(h0b) : "s"(A2), "s"(z));
  }

#pragma unroll 1
  for (int c = 0; c < 64; ++c) {
    unsigned coff  = (unsigned)(c << 8);                    // c * 256 B
    unsigned cnoff = (unsigned)((c < 63 ? c + 1 : 63) << 8); // clamped: no OOB prefetch
    float a0 = 0.f, a1 = 0.f, a2 = 0.f, a3 = 0.f;
    // wait for current row's first half (issued last iteration / prologue)
    asm volatile("s_waitcnt lgkmcnt(0)");
    __builtin_amdgcn_sched_barrier(0);
    // issue current row's second half (volatile: stays after the wait)
    asm volatile(
      "s_load_dwordx16 %0, %2, %3 offset:0x80\n\t"
      "s_load_dwordx16 %1, %2, %3 offset:0xc0"
      : "=s"(h1a), "=s"(h1b) : "s"(A2), "s"(coff));
    FMA16(h0a, 0)
    FMA16(h0b, 16)
    asm volatile("s_waitcnt lgkmcnt(0)");
    __builtin_amdgcn_sched_barrier(0);
    // issue next row's first half; overlaps with second-half FMAs
    asm volatile(
      "s_load_dwordx16 %0, %2, %3 offset:0x0\n\t"
      "s_load_dwordx16 %1, %2, %3 offset:0x40"
      : "=s"(h0a), "=s"(h0b) : "s"(A2), "s"(cnoff));
    FMA16(h1a, 32)
    FMA16(h1b, 48)
    float r = (a0 + a1) + (a2 + a3);
    __builtin_nontemporal_store(r, op + ((size_t)c << 14));
  }
#undef FMA16
  // drain the final (dead) prefetch before s_endpgm — pending SMEM writeback
  // after SGPR dealloc corrupts other waves.
  asm volatile("s_waitcnt lgkmcnt(0)");
}

// ---------------------------------------------------------------------------
extern "C" void kernel_launch(void* const* d_in, const int* in_sizes, int n_in,
                              void* d_out, int out_size, void* d_ws, size_t ws_size,
                              hipStream_t stream) {
  const float* x    = (const float*)d_in[0];
  const float* Wp   = (const float*)d_in[1];
  const float* w1   = (const float*)d_in[2];
  const float* b1   = (const float*)d_in[3];
  const float* w2   = (const float*)d_in[4];
  const float* b2   = (const float*)d_in[5];
  const float* beta = (const float*)d_in[6];
  const float* gres = (const float*)d_in[7];
  const float* temp = (const float*)d_in[8];

  // workspace layout
  double* statT = (double*)d_ws;                                    // 512 KB
  double* Z     = (double*)((char*)d_ws + (512 << 10));             // 32 KB
  float*  A2    = (float*)((char*)d_ws + (512 << 10) + (32 << 10)); // 16 KB

  float* out  = (float*)d_out;
  float* Aout = out + (size_t)B_N * C_N * W_N * T_N;                // 67108864

  k_stats<<<16384, 256, 0, stream>>>(x, statT);
  k_embed<<<1024, 256, 0, stream>>>(statT, Wp, Z);
  k_graph<<<1, 1024, 0, stream>>>(Z, w1, b1, w2, b2, beta, gres, temp, Aout, A2);
  k_prop<<<4096, 256, 0, stream>>>(x, A2, out);
}